// Round 8
// baseline (178.946 us; speedup 1.0000x reference)
//
#include <hip/hip_runtime.h>

#define B_N 128
#define C_N 1024
#define HW_N 192
#define CI_N 512
#define MROWS (B_N * HW_N)   // 24576 flat rows

typedef short bf16x8 __attribute__((ext_vector_type(8)));
typedef float f32x4 __attribute__((ext_vector_type(4)));
typedef unsigned short us4 __attribute__((ext_vector_type(4)));
typedef unsigned short us8 __attribute__((ext_vector_type(8)));

__device__ __forceinline__ unsigned short f2bf(float f){
    unsigned int u = __builtin_bit_cast(unsigned int, f);
    u += 0x7fffu + ((u >> 16) & 1u);   // round-to-nearest-even
    return (unsigned short)(u >> 16);
}
__device__ __forceinline__ float bf2f(unsigned short h){
    unsigned int u = ((unsigned int)h) << 16;
    return __builtin_bit_cast(float, u);
}
__device__ __forceinline__ void gload_lds16(const void* g, void* l){
    __builtin_amdgcn_global_load_lds(
        (const __attribute__((address_space(1))) unsigned int*)g,
        (__attribute__((address_space(3))) unsigned int*)l, 16, 0, 0);
}

// ---- prep: x (B,C,HW) f32  ->  xbT (B,HW,C) bf16 (transpose + convert) ----
__global__ __launch_bounds__(256) void k_prep_x(const float* __restrict__ x,
                                                unsigned short* __restrict__ xbT){
    __shared__ float tile[64][37];
    int b  = blockIdx.z;
    int c0 = blockIdx.y * 64;
    int n0 = blockIdx.x * 32;
    int t  = threadIdx.x;
    const float* xp = x + (size_t)b * C_N * HW_N;
    int cr = t >> 3;          // 0..31
    int nw = (t & 7) * 4;     // 0..28
    #pragma unroll
    for (int i = 0; i < 2; ++i){
        float4 v = *(const float4*)(xp + (size_t)(c0 + cr + 32 * i) * HW_N + n0 + nw);
        tile[cr + 32 * i][nw + 0] = v.x;
        tile[cr + 32 * i][nw + 1] = v.y;
        tile[cr + 32 * i][nw + 2] = v.z;
        tile[cr + 32 * i][nw + 3] = v.w;
    }
    __syncthreads();
    int nl = t >> 3;          // 0..31 output row (n)
    int j  = t & 7;           // 8-elem c group
    us8 pk;
    #pragma unroll
    for (int e = 0; e < 8; ++e)
        pk[e] = f2bf(tile[j * 8 + e][nl]);
    *(us8*)(xbT + (size_t)(b * HW_N + n0 + nl) * C_N + c0 + j * 8) = pk;
}

// ---- prep: Wcat = [theta_w; phi_w] -> bf16 (1024x1024), bias concat, w1 bf16
__global__ __launch_bounds__(256) void k_prep_w(const float* __restrict__ tw, const float* __restrict__ tb,
                                                const float* __restrict__ pw, const float* __restrict__ pb,
                                                const float* __restrict__ m1w,
                                                unsigned short* __restrict__ Wc, float* __restrict__ bias,
                                                unsigned short* __restrict__ w1b){
    int i = blockIdx.x * 256 + threadIdx.x;    // over 1024*1024
    int o = i >> 10, c = i & 1023;
    float v = (o < 512) ? tw[(size_t)o * 1024 + c] : pw[(size_t)(o - 512) * 1024 + c];
    Wc[i] = f2bf(v);
    if (i < 1024) bias[i] = (i < 512) ? tb[i] : pb[i - 512];
    if (i < 64 * HW_N) w1b[i] = f2bf(m1w[i]);
}

// ---- GEMM1: 256x256 tile, BK=64, 4-phase/K-tile pipelined schedule --------
// 512 thr = 8 waves (2M x 4N), per-wave C = 128n x 64o. LDS 128KB dbuf.
// Per K-tile: ph0 {stage W0(next); vmcnt(2); bar; ds_read Wfrags+Xq0; lgkm;
// setprio MFMA q0; bar} ; ph1-3 {ds_read Xqp; stage chunk p(next); bar; lgkm;
// setprio MFMA qp; bar}. Loads never drain to 0 mid-loop (T3+T4); swizzled
// LDS (T2, rule 21: pre-swizzled global src + swizzled ds_read); setprio (T5).
__global__ __launch_bounds__(512, 2) void k_gemm1(const unsigned short* __restrict__ Wc,
                                               const float* __restrict__ bias,
                                               const unsigned short* __restrict__ xbT,
                                               unsigned short* __restrict__ TPt,
                                               float2* __restrict__ part){
    __shared__ __align__(16) unsigned short lW[2][256 * 64];  // 2 x 32KB, rows = o
    __shared__ __align__(16) unsigned short lX[2][256 * 64];  // 2 x 32KB, rows = n
    int bid  = blockIdx.x;
    int xcd  = bid & 7;
    int slot = bid >> 3;                // 0..47
    int mb = xcd * 12 + (slot >> 2);    // n-tile (0..95)
    int nb = slot & 3;                  // o-tile (0..3)
    int tid = threadIdx.x, lane = tid & 63, wave = tid >> 6;
    int wm = wave >> 2, wn = wave & 3;  // 2 x 4 wave grid
    int fr = lane & 15, fg = lane >> 4;

    const unsigned short* Wg = Wc  + (size_t)(nb * 256) * C_N;
    const unsigned short* Xg = xbT + (size_t)(mb * 256) * C_N;

    // staging: chunk c (0,1 = W rows 0-127/128-255; 2,3 = X same), 16KB each.
    // thread t: issue i covers row (t>>3) + 64*i (+128 for odd chunk), unit t&7.
    int row0 = tid >> 3;                 // 0..63
    int su   = tid & 7;
    int gsw  = (su ^ (row0 & 7)) * 8;    // pre-swizzled global col; (row+64i)&7 == row&7
    const unsigned short* wsrc = Wg + (size_t)row0 * C_N + gsw;
    const unsigned short* xsrc = Xg + (size_t)row0 * C_N + gsw;

#define STAGE_CHUNK(c, buf, kcol)                                                         \
    do {                                                                                  \
        const unsigned short* _b = ((c) < 2 ? wsrc : xsrc) + (size_t)(((c)&1) * 128) * C_N + (kcol); \
        char* _d = (char*)((c) < 2 ? lW[buf] : lX[buf]) + ((c)&1) * 16384 + tid * 16;     \
        gload_lds16(_b, _d);                                                              \
        gload_lds16(_b + (size_t)64 * C_N, _d + 8192);                                    \
    } while (0)

    f32x4 acc[8][4];
    f32x4 zero = {0.f, 0.f, 0.f, 0.f};
    #pragma unroll
    for (int i = 0; i < 8; ++i)
        #pragma unroll
        for (int j = 0; j < 4; ++j)
            acc[i][j] = zero;

    // prologue: stage tile 0 into buffer 0 (8 gloads)
    STAGE_CHUNK(0, 0, 0);
    STAGE_CHUNK(1, 0, 0);
    STAGE_CHUNK(2, 0, 0);
    STAGE_CHUNK(3, 0, 0);

    for (int kt = 0; kt < 16; ++kt){
        int cur = kt & 1, nxt = cur ^ 1;
        int k1 = (kt + 1) * 64;
        bool pre = (kt < 15);

        // ---- phase 0 ----
        if (pre){
            STAGE_CHUNK(0, nxt, k1);
            asm volatile("s_waitcnt vmcnt(2)" ::: "memory");   // tile kt landed; 2 in flight
        } else {
            asm volatile("s_waitcnt vmcnt(0)" ::: "memory");
        }
        __builtin_amdgcn_sched_barrier(0);
        __builtin_amdgcn_s_barrier();

        bf16x8 wf[4][2];
        #pragma unroll
        for (int j = 0; j < 4; ++j){
            int row = wn * 64 + j * 16 + fr;
            #pragma unroll
            for (int kk = 0; kk < 2; ++kk)
                wf[j][kk] = *(const bf16x8*)((const char*)lW[cur] + row * 128 + (((kk * 4 + fg) ^ (row & 7)) * 16));
        }
        {
            bf16x8 xf[2][2];
            #pragma unroll
            for (int di = 0; di < 2; ++di){
                int row = wm * 128 + di * 16 + fr;     // quadrant 0: n-frags 0,1
                #pragma unroll
                for (int kk = 0; kk < 2; ++kk)
                    xf[di][kk] = *(const bf16x8*)((const char*)lX[cur] + row * 128 + (((kk * 4 + fg) ^ (row & 7)) * 16));
            }
            asm volatile("s_waitcnt lgkmcnt(0)" ::: "memory");
            __builtin_amdgcn_sched_barrier(0);
            __builtin_amdgcn_s_setprio(1);
            #pragma unroll
            for (int kk = 0; kk < 2; ++kk)
                #pragma unroll
                for (int di = 0; di < 2; ++di)
                    #pragma unroll
                    for (int j = 0; j < 4; ++j)
                        acc[di][j] = __builtin_amdgcn_mfma_f32_16x16x32_bf16(wf[j][kk], xf[di][kk], acc[di][j], 0, 0, 0);
            __builtin_amdgcn_s_setprio(0);
        }
        __builtin_amdgcn_s_barrier();

        // ---- phases 1..3 ----
        #pragma unroll
        for (int p = 1; p < 4; ++p){
            bf16x8 xf[2][2];
            #pragma unroll
            for (int di = 0; di < 2; ++di){
                int row = wm * 128 + (p * 2 + di) * 16 + fr;
                #pragma unroll
                for (int kk = 0; kk < 2; ++kk)
                    xf[di][kk] = *(const bf16x8*)((const char*)lX[cur] + row * 128 + (((kk * 4 + fg) ^ (row & 7)) * 16));
            }
            if (pre){
                if (p == 1) STAGE_CHUNK(1, nxt, k1);
                if (p == 2) STAGE_CHUNK(2, nxt, k1);
                if (p == 3) STAGE_CHUNK(3, nxt, k1);
            }
            __builtin_amdgcn_s_barrier();
            asm volatile("s_waitcnt lgkmcnt(0)" ::: "memory");
            __builtin_amdgcn_sched_barrier(0);
            __builtin_amdgcn_s_setprio(1);
            #pragma unroll
            for (int kk = 0; kk < 2; ++kk)
                #pragma unroll
                for (int di = 0; di < 2; ++di)
                    #pragma unroll
                    for (int j = 0; j < 4; ++j)
                        acc[p * 2 + di][j] = __builtin_amdgcn_mfma_f32_16x16x32_bf16(wf[j][kk], xf[di][kk], acc[p * 2 + di][j], 0, 0, 0);
            __builtin_amdgcn_s_setprio(0);
            __builtin_amdgcn_s_barrier();
        }
    }
#undef STAGE_CHUNK

    // epilogue: D[row=o (fg*4+r within frag j), col=n (fr within frag i)]
    float s[8], q[8];
    #pragma unroll
    for (int i = 0; i < 8; ++i){ s[i] = 0.f; q[i] = 0.f; }
    #pragma unroll
    for (int i = 0; i < 8; ++i){
        int n = mb * 256 + wm * 128 + i * 16 + fr;
        #pragma unroll
        for (int j = 0; j < 4; ++j){
            int o0 = nb * 256 + wn * 64 + j * 16 + fg * 4;
            float4 b4 = *(const float4*)(bias + o0);
            float v0 = acc[i][j][0] + b4.x;
            float v1 = acc[i][j][1] + b4.y;
            float v2 = acc[i][j][2] + b4.z;
            float v3 = acc[i][j][3] + b4.w;
            s[i] += v0 + v1 + v2 + v3;
            q[i] += v0*v0 + v1*v1 + v2*v2 + v3*v3;
            us4 pk;
            pk[0] = f2bf(v0); pk[1] = f2bf(v1); pk[2] = f2bf(v2); pk[3] = f2bf(v3);
            *(us4*)(TPt + (size_t)n * 1024 + o0) = pk;
        }
    }
    #pragma unroll
    for (int i = 0; i < 8; ++i){
        s[i] += __shfl_xor(s[i], 16); s[i] += __shfl_xor(s[i], 32);
        q[i] += __shfl_xor(q[i], 16); q[i] += __shfl_xor(q[i], 32);
    }
    if (fg == 0){
        int chunk = nb * 4 + wn;   // 64-col chunk index (0..15)
        #pragma unroll
        for (int i = 0; i < 8; ++i){
            int n = mb * 256 + wm * 128 + i * 16 + fr;
            part[(size_t)n * 16 + chunk] = make_float2(s[i], q[i]);
        }
    }
}

// ---- fold partials -> per-(row, half) mean & 1/(std+eps), ddof=1 ----------
__global__ __launch_bounds__(256) void k_stats(const float2* __restrict__ part,
                                               float2* __restrict__ stats){
    int idx = blockIdx.x * 256 + threadIdx.x;   // over MROWS*2, exact
    int n = idx >> 1, h = idx & 1;
    const float2* p = part + (size_t)n * 16 + h * 8;
    float S = 0.f, Q = 0.f;
    #pragma unroll
    for (int k = 0; k < 8; ++k){ float2 v = p[k]; S += v.x; Q += v.y; }
    float mean = S * (1.f / 512.f);
    float var  = (Q - 512.f * mean * mean) * (1.f / 511.f);
    float inv  = 1.f / (sqrtf(fmaxf(var, 0.f)) + 1e-4f);
    stats[idx] = make_float2(mean, inv);
}

// ---- GEMM2 + mask head fused (R6 proven) ----------------------------------
__global__ __launch_bounds__(256) void k_gemm2m(const unsigned short* __restrict__ TPt,
        const float2* __restrict__ stats,
        const unsigned short* __restrict__ w1b, const float* __restrict__ m1b,
        const float* __restrict__ bng, const float* __restrict__ bnb,
        const float* __restrict__ bnm, const float* __restrict__ bnv,
        const float* __restrict__ m2w, const float* __restrict__ m2b,
        float* __restrict__ mask){
    __shared__ __align__(16) unsigned short lT[64 * 64];    // 8KB  theta
    __shared__ __align__(16) unsigned short lP[192 * 64];   // 24KB phi
    __shared__ __align__(16) unsigned short lF[64 * 200];   // 25.6KB F-tile (pad 200)
    int tn = blockIdx.x;    // theta 64-row panel (0..2)
    int b  = blockIdx.y;
    int tid = threadIdx.x, lane = tid & 63, wave = tid >> 6;
    int wr = wave >> 1, wc = wave & 1;
    int fr = lane & 15, fg = lane >> 4;

    int rbase = tid >> 3;   // 0..31
    int su    = tid & 7;
    const unsigned short* src[8];
    float2 st[8];
    unsigned short* dst[8];
    #pragma unroll
    for (int i = 0; i < 8; ++i){
        int srow = rbase + 32 * i;
        int swz  = (su ^ (srow & 7)) * 16;
        if (i < 2){
            int gn = b * HW_N + tn * 64 + srow;
            src[i] = TPt + (size_t)gn * 1024 + su * 8;
            st[i]  = stats[(size_t)gn * 2 + 0];
            dst[i] = (unsigned short*)((char*)lT + srow * 128 + swz);
        } else {
            int prow = srow - 64;             // 0..191
            int gm = b * HW_N + prow;
            src[i] = TPt + (size_t)gm * 1024 + 512 + su * 8;
            st[i]  = stats[(size_t)gm * 2 + 1];
            dst[i] = (unsigned short*)((char*)lP + prow * 128 + swz);
        }
    }

    f32x4 acc[3][2][2];
    f32x4 zero = {0.f, 0.f, 0.f, 0.f};
    #pragma unroll
    for (int t = 0; t < 3; ++t)
        #pragma unroll
        for (int i = 0; i < 2; ++i)
            #pragma unroll
            for (int j = 0; j < 2; ++j)
                acc[t][i][j] = zero;

    for (int k0 = 0; k0 < CI_N; k0 += 64){
        bf16x8 nv[8];
        #pragma unroll
        for (int i = 0; i < 8; ++i){
            bf16x8 v = *(const bf16x8*)(src[i] + k0);
            #pragma unroll
            for (int e = 0; e < 8; ++e)
                nv[i][e] = (short)f2bf((bf2f((unsigned short)v[e]) - st[i].x) * st[i].y);
        }
        __syncthreads();
        #pragma unroll
        for (int i = 0; i < 8; ++i)
            *(bf16x8*)dst[i] = nv[i];
        __syncthreads();

        #pragma unroll
        for (int kk = 0; kk < 2; ++kk){
            bf16x8 tf[2];
            #pragma unroll
            for (int i = 0; i < 2; ++i){
                int row = wr * 32 + i * 16 + fr;
                int un  = (kk * 4 + fg) ^ (row & 7);
                tf[i] = *(const bf16x8*)((char*)lT + row * 128 + un * 16);
            }
            #pragma unroll
            for (int t = 0; t < 3; ++t){
                #pragma unroll
                for (int j = 0; j < 2; ++j){
                    int row = t * 64 + wc * 32 + j * 16 + fr;
                    int un  = (kk * 4 + fg) ^ (row & 7);
                    bf16x8 pf = *(const bf16x8*)((char*)lP + row * 128 + un * 16);
                    #pragma unroll
                    for (int i = 0; i < 2; ++i)
                        acc[t][i][j] = __builtin_amdgcn_mfma_f32_16x16x32_bf16(pf, tf[i], acc[t][i][j], 0, 0, 0);
                }
            }
        }
    }

    __syncthreads();
    #pragma unroll
    for (int t = 0; t < 3; ++t)
        #pragma unroll
        for (int i = 0; i < 2; ++i){
            int n = wr * 32 + i * 16 + fr;
            #pragma unroll
            for (int j = 0; j < 2; ++j){
                int m0 = t * 64 + wc * 32 + j * 16 + fg * 4;
                us4 pk;
                #pragma unroll
                for (int r = 0; r < 4; ++r)
                    pk[r] = f2bf(acc[t][i][j][r] * (1.0f / 512.0f));
                *(us4*)((char*)lF + ((size_t)n * 200 + m0) * 2) = pk;
            }
        }
    __syncthreads();

    f32x4 macc[4];
    #pragma unroll
    for (int j = 0; j < 4; ++j) macc[j] = zero;
    #pragma unroll
    for (int kk = 0; kk < 6; ++kk){
        bf16x8 af = *(const bf16x8*)((char*)lF + ((size_t)(wave * 16 + fr) * 200 + kk * 32 + fg * 8) * 2);
        #pragma unroll
        for (int j = 0; j < 4; ++j){
            bf16x8 bfv = *(const bf16x8*)(w1b + (size_t)(j * 16 + fr) * HW_N + kk * 32 + fg * 8);
            macc[j] = __builtin_amdgcn_mfma_f32_16x16x32_bf16(af, bfv, macc[j], 0, 0, 0);
        }
    }
    float sc[4], sh[4], bb[4], w2v[4];
    #pragma unroll
    for (int j = 0; j < 4; ++j){
        int o = j * 16 + fr;
        float s = bng[o] * rsqrtf(bnv[o] + 1e-5f);
        sc[j] = s;
        sh[j] = bnb[o] - bnm[o] * s;
        bb[j] = m1b[o];
        w2v[j] = m2w[o];
    }
    float mb2 = m2b[0];
    #pragma unroll
    for (int r = 0; r < 4; ++r){
        float y = 0.f;
        #pragma unroll
        for (int j = 0; j < 4; ++j){
            float t = fmaxf((macc[j][r] + bb[j]) * sc[j] + sh[j], 0.f);
            y += t * w2v[j];
        }
        y += __shfl_xor(y, 1);
        y += __shfl_xor(y, 2);
        y += __shfl_xor(y, 4);
        y += __shfl_xor(y, 8);
        if (fr == 0)
            mask[(size_t)b * HW_N + tn * 64 + wave * 16 + fg * 4 + r] = 1.f / (1.f + __expf(-(y + mb2)));
    }
}

// ---- apply: out = x * (1 + mask) ------------------------------------------
__global__ __launch_bounds__(256) void k_apply(const float* __restrict__ x,
                                               const float* __restrict__ mask,
                                               float* __restrict__ out){
    size_t i4 = (size_t)blockIdx.x * 256 + threadIdx.x;
    size_t e  = i4 * 4;
    float4 v = ((const float4*)x)[i4];
    size_t n = e % HW_N;                        // 192 % 4 == 0: same row for all 4
    size_t b = e / ((size_t)C_N * HW_N);
    const float* mk = mask + b * HW_N + n;
    float4 o;
    o.x = v.x * (1.f + mk[0]);
    o.y = v.y * (1.f + mk[1]);
    o.z = v.z * (1.f + mk[2]);
    o.w = v.w * (1.f + mk[3]);
    ((float4*)out)[i4] = o;
}

extern "C" void kernel_launch(void* const* d_in, const int* in_sizes, int n_in,
                              void* d_out, int out_size, void* d_ws, size_t ws_size,
                              hipStream_t stream){
    (void)in_sizes; (void)n_in; (void)out_size; (void)ws_size;
    const float* x   = (const float*)d_in[0];
    const float* tw  = (const float*)d_in[1];
    const float* tb  = (const float*)d_in[2];
    const float* pw  = (const float*)d_in[3];
    const float* pb  = (const float*)d_in[4];
    const float* m1w = (const float*)d_in[5];
    const float* m1b = (const float*)d_in[6];
    const float* bng = (const float*)d_in[7];
    const float* bnb = (const float*)d_in[8];
    const float* bnm = (const float*)d_in[9];
    const float* bnv = (const float*)d_in[10];
    const float* m2w = (const float*)d_in[11];
    const float* m2b = (const float*)d_in[12];
    float* out = (float*)d_out;

    char* ws = (char*)d_ws;
    size_t off = 0;
    unsigned short* xbT = (unsigned short*)(ws + off); off += (size_t)MROWS * C_N * 2;        // 48 MB
    unsigned short* Wc  = (unsigned short*)(ws + off); off += (size_t)1024 * 1024 * 2;        // 2 MB
    float* bias         = (float*)(ws + off);          off += 4096;
    unsigned short* TPt = (unsigned short*)(ws + off); off += (size_t)MROWS * 1024 * 2;       // 48 MB
    float* mask         = (float*)(ws + off);          off += (size_t)MROWS * 4;
    unsigned short* w1b = (unsigned short*)(ws + off); off += (size_t)64 * HW_N * 2;
    off = (off + 255) & ~(size_t)255;
    float2* part        = (float2*)(ws + off);         off += (size_t)MROWS * 16 * 8;         // 3 MB
    float2* stats       = (float2*)(ws + off);         off += (size_t)MROWS * 2 * 8;          // 0.4 MB

    k_prep_x<<<dim3(6, 16, B_N), 256, 0, stream>>>(x, xbT);
    k_prep_w<<<dim3(4096), 256, 0, stream>>>(tw, tb, pw, pb, m1w, Wc, bias, w1b);
    k_gemm1<<<dim3(384), 512, 0, stream>>>(Wc, bias, xbT, TPt, part);
    k_stats<<<dim3(MROWS * 2 / 256), 256, 0, stream>>>(part, stats);
    k_gemm2m<<<dim3(3, B_N), 256, 0, stream>>>(TPt, stats, w1b, m1b, bng, bnb, bnm, bnv, m2w, m2b, mask);
    k_apply<<<dim3(MROWS * C_N / 4 / 256), 256, 0, stream>>>(x, mask, out);
}

// Round 9
// 161.813 us; speedup vs baseline: 1.1059x; 1.1059x over previous
//
#include <hip/hip_runtime.h>

#define B_N 128
#define C_N 1024
#define HW_N 192
#define CI_N 512
#define MROWS (B_N * HW_N)   // 24576 flat rows

typedef short bf16x8 __attribute__((ext_vector_type(8)));
typedef float f32x4 __attribute__((ext_vector_type(4)));
typedef unsigned short us4 __attribute__((ext_vector_type(4)));
typedef unsigned short us8 __attribute__((ext_vector_type(8)));

__device__ __forceinline__ unsigned short f2bf(float f){
    unsigned int u = __builtin_bit_cast(unsigned int, f);
    u += 0x7fffu + ((u >> 16) & 1u);   // round-to-nearest-even
    return (unsigned short)(u >> 16);
}
__device__ __forceinline__ float bf2f(unsigned short h){
    unsigned int u = ((unsigned int)h) << 16;
    return __builtin_bit_cast(float, u);
}
__device__ __forceinline__ void gload_lds16(const void* g, void* l){
    __builtin_amdgcn_global_load_lds(
        (const __attribute__((address_space(1))) unsigned int*)g,
        (__attribute__((address_space(3))) unsigned int*)l, 16, 0, 0);
}

// ---- prep (fused): x transpose->bf16  AND  Wcat/bias/w1 conversion --------
__global__ __launch_bounds__(256) void k_prep(const float* __restrict__ x,
                                              unsigned short* __restrict__ xbT,
                                              const float* __restrict__ tw, const float* __restrict__ tb,
                                              const float* __restrict__ pw, const float* __restrict__ pb,
                                              const float* __restrict__ m1w,
                                              unsigned short* __restrict__ Wc, float* __restrict__ bias,
                                              unsigned short* __restrict__ w1b){
    __shared__ float tile[64][37];
    int b  = blockIdx.z;
    int c0 = blockIdx.y * 64;
    int n0 = blockIdx.x * 32;
    int t  = threadIdx.x;

    // fused weight prep: first 4096 block-equivalents handle Wc (1M elems)
    int fid = ((blockIdx.z * gridDim.y + blockIdx.y) * gridDim.x + blockIdx.x) * 256 + t;
    if (fid < 1024 * 1024){
        int o = fid >> 10, c = fid & 1023;
        float v = (o < 512) ? tw[(size_t)o * 1024 + c] : pw[(size_t)(o - 512) * 1024 + c];
        Wc[fid] = f2bf(v);
        if (fid < 1024) bias[fid] = (fid < 512) ? tb[fid] : pb[fid - 512];
        if (fid < 64 * HW_N) w1b[fid] = f2bf(m1w[fid]);
    }

    const float* xp = x + (size_t)b * C_N * HW_N;
    int cr = t >> 3;          // 0..31
    int nw = (t & 7) * 4;     // 0..28
    #pragma unroll
    for (int i = 0; i < 2; ++i){
        float4 v = *(const float4*)(xp + (size_t)(c0 + cr + 32 * i) * HW_N + n0 + nw);
        tile[cr + 32 * i][nw + 0] = v.x;
        tile[cr + 32 * i][nw + 1] = v.y;
        tile[cr + 32 * i][nw + 2] = v.z;
        tile[cr + 32 * i][nw + 3] = v.w;
    }
    __syncthreads();
    int nl = t >> 3;          // 0..31 output row (n)
    int j  = t & 7;           // 8-elem c group
    us8 pk;
    #pragma unroll
    for (int e = 0; e < 8; ++e)
        pk[e] = f2bf(tile[j * 8 + e][nl]);
    *(us8*)(xbT + (size_t)(b * HW_N + n0 + nl) * C_N + c0 + j * 8) = pk;
}

// ---- GEMM1 (R4 proven: 128x128, BK=64, XCD-remapped, 2-barrier m97) -------
__global__ __launch_bounds__(256, 3) void k_gemm1(const unsigned short* __restrict__ Wc,
                                               const float* __restrict__ bias,
                                               const unsigned short* __restrict__ xbT,
                                               unsigned short* __restrict__ TPt,
                                               float2* __restrict__ part){
    __shared__ __align__(16) unsigned short lW[128 * 64];  // 16KB, rows = o
    __shared__ __align__(16) unsigned short lX[128 * 64];  // 16KB, rows = n
    int bid  = blockIdx.x;
    int xcd  = bid & 7;
    int slot = bid >> 3;
    int mb = xcd * 24 + (slot >> 3);   // n-tile (0..191)
    int nb = slot & 7;                 // o-tile (0..7)
    int tid = threadIdx.x, lane = tid & 63, wave = tid >> 6;
    int wr = wave >> 1, wc = wave & 1;
    int fr = lane & 15, fg = lane >> 4;

    const unsigned short* Wg = Wc  + (size_t)(nb * 128) * C_N;
    const unsigned short* Xg = xbT + (size_t)(mb * 128) * C_N;

    int row0 = tid >> 3;                 // 0..31
    int su   = tid & 7;
    int gsw  = (su ^ (row0 & 7)) * 8;    // pre-swizzled global col (elems)
    const unsigned short* wsrc = Wg + (size_t)row0 * C_N + gsw;
    const unsigned short* xsrc = Xg + (size_t)row0 * C_N + gsw;

    f32x4 acc[4][4];
    f32x4 zero = {0.f, 0.f, 0.f, 0.f};
    #pragma unroll
    for (int i = 0; i < 4; ++i)
        #pragma unroll
        for (int j = 0; j < 4; ++j)
            acc[i][j] = zero;

    for (int k0 = 0; k0 < C_N; k0 += 64){
        __syncthreads();
        #pragma unroll
        for (int i = 0; i < 4; ++i){
            gload_lds16(wsrc + (size_t)(32 * i) * C_N + k0, (char*)lW + tid * 16 + i * 4096);
            gload_lds16(xsrc + (size_t)(32 * i) * C_N + k0, (char*)lX + tid * 16 + i * 4096);
        }
        __syncthreads();   // compiler drains vmcnt(0) here (m97 structure)

        #pragma unroll
        for (int kk = 0; kk < 2; ++kk){
            bf16x8 wf[4], xf[4];
            #pragma unroll
            for (int j = 0; j < 4; ++j){
                int row = wc * 64 + j * 16 + fr;
                int un  = (kk * 4 + fg) ^ (row & 7);
                wf[j] = *(const bf16x8*)((char*)lW + row * 128 + un * 16);
            }
            #pragma unroll
            for (int i = 0; i < 4; ++i){
                int row = wr * 64 + i * 16 + fr;
                int un  = (kk * 4 + fg) ^ (row & 7);
                xf[i] = *(const bf16x8*)((char*)lX + row * 128 + un * 16);
            }
            #pragma unroll
            for (int i = 0; i < 4; ++i)
                #pragma unroll
                for (int j = 0; j < 4; ++j)
                    acc[i][j] = __builtin_amdgcn_mfma_f32_16x16x32_bf16(wf[j], xf[i], acc[i][j], 0, 0, 0);
        }
    }

    // epilogue: D[row=o (fg*4+r within frag j), col=n (fr within frag i)]
    float s[4] = {0.f,0.f,0.f,0.f}, q[4] = {0.f,0.f,0.f,0.f};
    #pragma unroll
    for (int i = 0; i < 4; ++i){
        int n = mb * 128 + wr * 64 + i * 16 + fr;
        #pragma unroll
        for (int j = 0; j < 4; ++j){
            int o0 = nb * 128 + wc * 64 + j * 16 + fg * 4;
            float4 b4 = *(const float4*)(bias + o0);
            float v0 = acc[i][j][0] + b4.x;
            float v1 = acc[i][j][1] + b4.y;
            float v2 = acc[i][j][2] + b4.z;
            float v3 = acc[i][j][3] + b4.w;
            s[i] += v0 + v1 + v2 + v3;
            q[i] += v0*v0 + v1*v1 + v2*v2 + v3*v3;
            us4 pk;
            pk[0] = f2bf(v0); pk[1] = f2bf(v1); pk[2] = f2bf(v2); pk[3] = f2bf(v3);
            *(us4*)(TPt + (size_t)n * 1024 + o0) = pk;
        }
    }
    #pragma unroll
    for (int i = 0; i < 4; ++i){
        s[i] += __shfl_xor(s[i], 16); s[i] += __shfl_xor(s[i], 32);
        q[i] += __shfl_xor(q[i], 16); q[i] += __shfl_xor(q[i], 32);
    }
    if (lane < 16){   // fg == 0
        int chunk = nb * 2 + wc;   // 64-col chunk index (0..15)
        #pragma unroll
        for (int i = 0; i < 4; ++i){
            int n = mb * 128 + wr * 64 + i * 16 + fr;
            part[(size_t)n * 16 + chunk] = make_float2(s[i], q[i]);
        }
    }
}

// ---- GEMM2 + stats-fold + mask head fused. grid (3, B) --------------------
// Per staged row, fold its 8 part-chunk partials inline -> mean, 1/(std+eps).
// F-tile stays in LDS; mask output stored as (1 + sigmoid) for k_apply.
__global__ __launch_bounds__(256) void k_gemm2m(const unsigned short* __restrict__ TPt,
        const float2* __restrict__ part,
        const unsigned short* __restrict__ w1b, const float* __restrict__ m1b,
        const float* __restrict__ bng, const float* __restrict__ bnb,
        const float* __restrict__ bnm, const float* __restrict__ bnv,
        const float* __restrict__ m2w, const float* __restrict__ m2b,
        float* __restrict__ mask){
    __shared__ __align__(16) unsigned short lT[64 * 64];    // 8KB  theta
    __shared__ __align__(16) unsigned short lP[192 * 64];   // 24KB phi
    __shared__ __align__(16) unsigned short lF[64 * 200];   // 25.6KB F-tile (pad 200)
    int tn = blockIdx.x;    // theta 64-row panel (0..2)
    int b  = blockIdx.y;
    int tid = threadIdx.x, lane = tid & 63, wave = tid >> 6;
    int wr = wave >> 1, wc = wave & 1;
    int fr = lane & 15, fg = lane >> 4;

    int rbase = tid >> 3;   // 0..31
    int su    = tid & 7;
    const unsigned short* src[8];
    float2 st[8];
    unsigned short* dst[8];
    #pragma unroll
    for (int i = 0; i < 8; ++i){
        int srow = rbase + 32 * i;
        int swz  = (su ^ (srow & 7)) * 16;
        const float2* pp;
        if (i < 2){
            int gn = b * HW_N + tn * 64 + srow;
            src[i] = TPt + (size_t)gn * 1024 + su * 8;
            pp     = part + (size_t)gn * 16;          // theta chunks 0..7
            dst[i] = (unsigned short*)((char*)lT + srow * 128 + swz);
        } else {
            int prow = srow - 64;             // 0..191
            int gm = b * HW_N + prow;
            src[i] = TPt + (size_t)gm * 1024 + 512 + su * 8;
            pp     = part + (size_t)gm * 16 + 8;      // phi chunks 8..15
            dst[i] = (unsigned short*)((char*)lP + prow * 128 + swz);
        }
        float S = 0.f, Q = 0.f;
        #pragma unroll
        for (int k = 0; k < 8; ++k){ float2 v = pp[k]; S += v.x; Q += v.y; }
        float mean = S * (1.f / 512.f);
        float var  = (Q - 512.f * mean * mean) * (1.f / 511.f);
        st[i] = make_float2(mean, 1.f / (sqrtf(fmaxf(var, 0.f)) + 1e-4f));
    }

    f32x4 acc[3][2][2];
    f32x4 zero = {0.f, 0.f, 0.f, 0.f};
    #pragma unroll
    for (int t = 0; t < 3; ++t)
        #pragma unroll
        for (int i = 0; i < 2; ++i)
            #pragma unroll
            for (int j = 0; j < 2; ++j)
                acc[t][i][j] = zero;

    for (int k0 = 0; k0 < CI_N; k0 += 64){
        bf16x8 nv[8];
        #pragma unroll
        for (int i = 0; i < 8; ++i){
            bf16x8 v = *(const bf16x8*)(src[i] + k0);
            #pragma unroll
            for (int e = 0; e < 8; ++e)
                nv[i][e] = (short)f2bf((bf2f((unsigned short)v[e]) - st[i].x) * st[i].y);
        }
        __syncthreads();
        #pragma unroll
        for (int i = 0; i < 8; ++i)
            *(bf16x8*)dst[i] = nv[i];
        __syncthreads();

        #pragma unroll
        for (int kk = 0; kk < 2; ++kk){
            bf16x8 tf[2];
            #pragma unroll
            for (int i = 0; i < 2; ++i){
                int row = wr * 32 + i * 16 + fr;
                int un  = (kk * 4 + fg) ^ (row & 7);
                tf[i] = *(const bf16x8*)((char*)lT + row * 128 + un * 16);
            }
            #pragma unroll
            for (int t = 0; t < 3; ++t){
                #pragma unroll
                for (int j = 0; j < 2; ++j){
                    int row = t * 64 + wc * 32 + j * 16 + fr;
                    int un  = (kk * 4 + fg) ^ (row & 7);
                    bf16x8 pf = *(const bf16x8*)((char*)lP + row * 128 + un * 16);
                    #pragma unroll
                    for (int i = 0; i < 2; ++i)
                        acc[t][i][j] = __builtin_amdgcn_mfma_f32_16x16x32_bf16(pf, tf[i], acc[t][i][j], 0, 0, 0);
                }
            }
        }
    }

    __syncthreads();
    #pragma unroll
    for (int t = 0; t < 3; ++t)
        #pragma unroll
        for (int i = 0; i < 2; ++i){
            int n = wr * 32 + i * 16 + fr;
            #pragma unroll
            for (int j = 0; j < 2; ++j){
                int m0 = t * 64 + wc * 32 + j * 16 + fg * 4;
                us4 pk;
                #pragma unroll
                for (int r = 0; r < 4; ++r)
                    pk[r] = f2bf(acc[t][i][j][r] * (1.0f / 512.0f));
                *(us4*)((char*)lF + ((size_t)n * 200 + m0) * 2) = pk;
            }
        }
    __syncthreads();

    f32x4 macc[4];
    #pragma unroll
    for (int j = 0; j < 4; ++j) macc[j] = zero;
    #pragma unroll
    for (int kk = 0; kk < 6; ++kk){
        bf16x8 af = *(const bf16x8*)((char*)lF + ((size_t)(wave * 16 + fr) * 200 + kk * 32 + fg * 8) * 2);
        #pragma unroll
        for (int j = 0; j < 4; ++j){
            bf16x8 bfv = *(const bf16x8*)(w1b + (size_t)(j * 16 + fr) * HW_N + kk * 32 + fg * 8);
            macc[j] = __builtin_amdgcn_mfma_f32_16x16x32_bf16(af, bfv, macc[j], 0, 0, 0);
        }
    }
    float sc[4], sh[4], bb[4], w2v[4];
    #pragma unroll
    for (int j = 0; j < 4; ++j){
        int o = j * 16 + fr;
        float s = bng[o] * rsqrtf(bnv[o] + 1e-5f);
        sc[j] = s;
        sh[j] = bnb[o] - bnm[o] * s;
        bb[j] = m1b[o];
        w2v[j] = m2w[o];
    }
    float mb2 = m2b[0];
    #pragma unroll
    for (int r = 0; r < 4; ++r){
        float y = 0.f;
        #pragma unroll
        for (int j = 0; j < 4; ++j){
            float t = fmaxf((macc[j][r] + bb[j]) * sc[j] + sh[j], 0.f);
            y += t * w2v[j];
        }
        y += __shfl_xor(y, 1);
        y += __shfl_xor(y, 2);
        y += __shfl_xor(y, 4);
        y += __shfl_xor(y, 8);
        if (fr == 0)
            mask[(size_t)b * HW_N + tn * 64 + wave * 16 + fg * 4 + r] =
                1.f + 1.f / (1.f + __expf(-(y + mb2)));   // store (1 + sigmoid)
    }
}

// ---- apply: out = x * mask1p  (mask1p = 1 + sigmoid) ----------------------
__global__ __launch_bounds__(256) void k_apply(const float* __restrict__ x,
                                               const float* __restrict__ mask,
                                               float* __restrict__ out){
    size_t i4 = (size_t)blockIdx.x * 256 + threadIdx.x;
    size_t e  = i4 * 4;
    float4 v = ((const float4*)x)[i4];
    size_t n = e % HW_N;                        // 192 % 4 == 0: same row for all 4
    size_t b = e / ((size_t)C_N * HW_N);
    const float* mk = mask + b * HW_N + n;
    float4 o;
    o.x = v.x * mk[0];
    o.y = v.y * mk[1];
    o.z = v.z * mk[2];
    o.w = v.w * mk[3];
    ((float4*)out)[i4] = o;
}

extern "C" void kernel_launch(void* const* d_in, const int* in_sizes, int n_in,
                              void* d_out, int out_size, void* d_ws, size_t ws_size,
                              hipStream_t stream){
    (void)in_sizes; (void)n_in; (void)out_size; (void)ws_size;
    const float* x   = (const float*)d_in[0];
    const float* tw  = (const float*)d_in[1];
    const float* tb  = (const float*)d_in[2];
    const float* pw  = (const float*)d_in[3];
    const float* pb  = (const float*)d_in[4];
    const float* m1w = (const float*)d_in[5];
    const float* m1b = (const float*)d_in[6];
    const float* bng = (const float*)d_in[7];
    const float* bnb = (const float*)d_in[8];
    const float* bnm = (const float*)d_in[9];
    const float* bnv = (const float*)d_in[10];
    const float* m2w = (const float*)d_in[11];
    const float* m2b = (const float*)d_in[12];
    float* out = (float*)d_out;

    char* ws = (char*)d_ws;
    size_t off = 0;
    unsigned short* xbT = (unsigned short*)(ws + off); off += (size_t)MROWS * C_N * 2;        // 48 MB
    unsigned short* Wc  = (unsigned short*)(ws + off); off += (size_t)1024 * 1024 * 2;        // 2 MB
    float* bias         = (float*)(ws + off);          off += 4096;
    unsigned short* TPt = (unsigned short*)(ws + off); off += (size_t)MROWS * 1024 * 2;       // 48 MB
    float* mask         = (float*)(ws + off);          off += (size_t)MROWS * 4;
    unsigned short* w1b = (unsigned short*)(ws + off); off += (size_t)64 * HW_N * 2;
    off = (off + 255) & ~(size_t)255;
    float2* part        = (float2*)(ws + off);         off += (size_t)MROWS * 16 * 8;         // 3 MB

    k_prep<<<dim3(6, 16, B_N), 256, 0, stream>>>(x, xbT, tw, tb, pw, pb, m1w, Wc, bias, w1b);
    k_gemm1<<<dim3(1536), 256, 0, stream>>>(Wc, bias, xbT, TPt, part);
    k_gemm2m<<<dim3(3, B_N), 256, 0, stream>>>(TPt, part, w1b, m1b, bng, bnb, bnm, bnv, m2w, m2b, mask);
    k_apply<<<dim3(MROWS * C_N / 4 / 256), 256, 0, stream>>>(x, mask, out);
}

// Round 10
// 144.835 us; speedup vs baseline: 1.2355x; 1.1172x over previous
//
#include <hip/hip_runtime.h>

#define B_N 128
#define C_N 1024
#define HW_N 192
#define CI_N 512
#define MROWS (B_N * HW_N)   // 24576 flat rows

typedef short bf16x8 __attribute__((ext_vector_type(8)));
typedef float f32x4 __attribute__((ext_vector_type(4)));
typedef unsigned short us4 __attribute__((ext_vector_type(4)));
typedef unsigned short us8 __attribute__((ext_vector_type(8)));

__device__ __forceinline__ unsigned short f2bf(float f){
    unsigned int u = __builtin_bit_cast(unsigned int, f);
    u += 0x7fffu + ((u >> 16) & 1u);   // round-to-nearest-even
    return (unsigned short)(u >> 16);
}
__device__ __forceinline__ float bf2f(unsigned short h){
    unsigned int u = ((unsigned int)h) << 16;
    return __builtin_bit_cast(float, u);
}
__device__ __forceinline__ void gload_lds16(const void* g, void* l){
    __builtin_amdgcn_global_load_lds(
        (const __attribute__((address_space(1))) unsigned int*)g,
        (__attribute__((address_space(3))) unsigned int*)l, 16, 0, 0);
}

// ---- prep (fused): x transpose->bf16  AND  Wcat/bias/w1 conversion --------
__global__ __launch_bounds__(256) void k_prep(const float* __restrict__ x,
                                              unsigned short* __restrict__ xbT,
                                              const float* __restrict__ tw, const float* __restrict__ tb,
                                              const float* __restrict__ pw, const float* __restrict__ pb,
                                              const float* __restrict__ m1w,
                                              unsigned short* __restrict__ Wc, float* __restrict__ bias,
                                              unsigned short* __restrict__ w1b){
    __shared__ float tile[64][37];
    int b  = blockIdx.z;
    int c0 = blockIdx.y * 64;
    int n0 = blockIdx.x * 32;
    int t  = threadIdx.x;

    int fid = ((blockIdx.z * gridDim.y + blockIdx.y) * gridDim.x + blockIdx.x) * 256 + t;
    if (fid < 1024 * 1024){
        int o = fid >> 10, c = fid & 1023;
        float v = (o < 512) ? tw[(size_t)o * 1024 + c] : pw[(size_t)(o - 512) * 1024 + c];
        Wc[fid] = f2bf(v);
        if (fid < 1024) bias[fid] = (fid < 512) ? tb[fid] : pb[fid - 512];
        if (fid < 64 * HW_N) w1b[fid] = f2bf(m1w[fid]);
    }

    const float* xp = x + (size_t)b * C_N * HW_N;
    int cr = t >> 3;          // 0..31
    int nw = (t & 7) * 4;     // 0..28
    #pragma unroll
    for (int i = 0; i < 2; ++i){
        float4 v = *(const float4*)(xp + (size_t)(c0 + cr + 32 * i) * HW_N + n0 + nw);
        tile[cr + 32 * i][nw + 0] = v.x;
        tile[cr + 32 * i][nw + 1] = v.y;
        tile[cr + 32 * i][nw + 2] = v.z;
        tile[cr + 32 * i][nw + 3] = v.w;
    }
    __syncthreads();
    int nl = t >> 3;          // 0..31 output row (n)
    int j  = t & 7;           // 8-elem c group
    us8 pk;
    #pragma unroll
    for (int e = 0; e < 8; ++e)
        pk[e] = f2bf(tile[j * 8 + e][nl]);
    *(us8*)(xbT + (size_t)(b * HW_N + n0 + nl) * C_N + c0 + j * 8) = pk;
}

// ---- GEMM1 (R4 proven: 128x128, BK=64, XCD-remapped, 2-barrier m97) -------
__global__ __launch_bounds__(256, 3) void k_gemm1(const unsigned short* __restrict__ Wc,
                                               const float* __restrict__ bias,
                                               const unsigned short* __restrict__ xbT,
                                               unsigned short* __restrict__ TPt,
                                               float2* __restrict__ part){
    __shared__ __align__(16) unsigned short lW[128 * 64];  // 16KB, rows = o
    __shared__ __align__(16) unsigned short lX[128 * 64];  // 16KB, rows = n
    int bid  = blockIdx.x;
    int xcd  = bid & 7;
    int slot = bid >> 3;
    int mb = xcd * 24 + (slot >> 3);   // n-tile (0..191)
    int nb = slot & 7;                 // o-tile (0..7)
    int tid = threadIdx.x, lane = tid & 63, wave = tid >> 6;
    int wr = wave >> 1, wc = wave & 1;
    int fr = lane & 15, fg = lane >> 4;

    const unsigned short* Wg = Wc  + (size_t)(nb * 128) * C_N;
    const unsigned short* Xg = xbT + (size_t)(mb * 128) * C_N;

    int row0 = tid >> 3;                 // 0..31
    int su   = tid & 7;
    int gsw  = (su ^ (row0 & 7)) * 8;    // pre-swizzled global col (elems)
    const unsigned short* wsrc = Wg + (size_t)row0 * C_N + gsw;
    const unsigned short* xsrc = Xg + (size_t)row0 * C_N + gsw;

    f32x4 acc[4][4];
    f32x4 zero = {0.f, 0.f, 0.f, 0.f};
    #pragma unroll
    for (int i = 0; i < 4; ++i)
        #pragma unroll
        for (int j = 0; j < 4; ++j)
            acc[i][j] = zero;

    for (int k0 = 0; k0 < C_N; k0 += 64){
        __syncthreads();
        #pragma unroll
        for (int i = 0; i < 4; ++i){
            gload_lds16(wsrc + (size_t)(32 * i) * C_N + k0, (char*)lW + tid * 16 + i * 4096);
            gload_lds16(xsrc + (size_t)(32 * i) * C_N + k0, (char*)lX + tid * 16 + i * 4096);
        }
        __syncthreads();   // compiler drains vmcnt(0) here (m97 structure)

        #pragma unroll
        for (int kk = 0; kk < 2; ++kk){
            bf16x8 wf[4], xf[4];
            #pragma unroll
            for (int j = 0; j < 4; ++j){
                int row = wc * 64 + j * 16 + fr;
                int un  = (kk * 4 + fg) ^ (row & 7);
                wf[j] = *(const bf16x8*)((char*)lW + row * 128 + un * 16);
            }
            #pragma unroll
            for (int i = 0; i < 4; ++i){
                int row = wr * 64 + i * 16 + fr;
                int un  = (kk * 4 + fg) ^ (row & 7);
                xf[i] = *(const bf16x8*)((char*)lX + row * 128 + un * 16);
            }
            #pragma unroll
            for (int i = 0; i < 4; ++i)
                #pragma unroll
                for (int j = 0; j < 4; ++j)
                    acc[i][j] = __builtin_amdgcn_mfma_f32_16x16x32_bf16(wf[j], xf[i], acc[i][j], 0, 0, 0);
        }
    }

    // epilogue: D[row=o (fg*4+r within frag j), col=n (fr within frag i)]
    float s[4] = {0.f,0.f,0.f,0.f}, q[4] = {0.f,0.f,0.f,0.f};
    #pragma unroll
    for (int i = 0; i < 4; ++i){
        int n = mb * 128 + wr * 64 + i * 16 + fr;
        #pragma unroll
        for (int j = 0; j < 4; ++j){
            int o0 = nb * 128 + wc * 64 + j * 16 + fg * 4;
            float4 b4 = *(const float4*)(bias + o0);
            float v0 = acc[i][j][0] + b4.x;
            float v1 = acc[i][j][1] + b4.y;
            float v2 = acc[i][j][2] + b4.z;
            float v3 = acc[i][j][3] + b4.w;
            s[i] += v0 + v1 + v2 + v3;
            q[i] += v0*v0 + v1*v1 + v2*v2 + v3*v3;
            us4 pk;
            pk[0] = f2bf(v0); pk[1] = f2bf(v1); pk[2] = f2bf(v2); pk[3] = f2bf(v3);
            *(us4*)(TPt + (size_t)n * 1024 + o0) = pk;
        }
    }
    #pragma unroll
    for (int i = 0; i < 4; ++i){
        s[i] += __shfl_xor(s[i], 16); s[i] += __shfl_xor(s[i], 32);
        q[i] += __shfl_xor(q[i], 16); q[i] += __shfl_xor(q[i], 32);
    }
    if (lane < 16){   // fg == 0
        int chunk = nb * 2 + wc;   // 64-col chunk index (0..15)
        #pragma unroll
        for (int i = 0; i < 4; ++i){
            int n = mb * 128 + wr * 64 + i * 16 + fr;
            part[(size_t)n * 16 + chunk] = make_float2(s[i], q[i]);
        }
    }
}

// ---- GEMM2 (raw, covariance identity) + stats-fold + mask head fused ------
// F[n][m] = invT[n]*invP[m]*(sum_c T[n,c]P[m,c] - 512*muT[n]*muP[m])/512.
// K-loop is a PURE gload_lds GEMM on raw TPt (no per-element z-score VALU);
// the z-score correction is applied per output element in the fp32 epilogue.
__global__ __launch_bounds__(256) void k_gemm2m(const unsigned short* __restrict__ TPt,
        const float2* __restrict__ part,
        const unsigned short* __restrict__ w1b, const float* __restrict__ m1b,
        const float* __restrict__ bng, const float* __restrict__ bnb,
        const float* __restrict__ bnm, const float* __restrict__ bnv,
        const float* __restrict__ m2w, const float* __restrict__ m2b,
        float* __restrict__ mask){
    __shared__ __align__(16) unsigned short lT[64 * 64];    // 8KB  theta (raw)
    __shared__ __align__(16) unsigned short lP[192 * 64];   // 24KB phi (raw)
    __shared__ __align__(16) unsigned short lF[64 * 200];   // 25.6KB F-tile (pad 200)
    __shared__ float2 stT[64];
    __shared__ float2 stP[192];
    int tn = blockIdx.x;    // theta 64-row panel (0..2)
    int b  = blockIdx.y;
    int tid = threadIdx.x, lane = tid & 63, wave = tid >> 6;
    int wr = wave >> 1, wc = wave & 1;
    int fr = lane & 15, fg = lane >> 4;

    // ---- stats fold: thread<64 -> theta row, others -> phi rows 0..191 ----
    {
        const float2* pp;
        if (tid < 64)
            pp = part + (size_t)(b * HW_N + tn * 64 + tid) * 16;        // theta chunks 0..7
        else
            pp = part + (size_t)(b * HW_N + (tid - 64)) * 16 + 8;       // phi chunks 8..15
        float S = 0.f, Q = 0.f;
        #pragma unroll
        for (int k = 0; k < 8; ++k){ float2 v = pp[k]; S += v.x; Q += v.y; }
        float mean = S * (1.f / 512.f);
        float var  = (Q - 512.f * mean * mean) * (1.f / 511.f);
        float2 r = make_float2(mean, 1.f / (sqrtf(fmaxf(var, 0.f)) + 1e-4f));
        if (tid < 64) stT[tid] = r; else stP[tid - 64] = r;
    }
    // (first K-loop barrier orders these stores before epilogue reads)

    // ---- staging setup (rule 21: pre-swizzled global src, swizzled read) --
    int row0 = tid >> 3;                 // 0..31
    int su   = tid & 7;
    int gsw  = (su ^ (row0 & 7)) * 8;    // (row0+32i)&7 == row0&7
    const unsigned short* tsrc = TPt + (size_t)(b * HW_N + tn * 64 + row0) * 1024 + gsw;
    const unsigned short* psrc = TPt + (size_t)(b * HW_N + row0) * 1024 + 512 + gsw;

    f32x4 acc[3][2][2];
    f32x4 zero = {0.f, 0.f, 0.f, 0.f};
    #pragma unroll
    for (int t = 0; t < 3; ++t)
        #pragma unroll
        for (int i = 0; i < 2; ++i)
            #pragma unroll
            for (int j = 0; j < 2; ++j)
                acc[t][i][j] = zero;

    for (int k0 = 0; k0 < CI_N; k0 += 64){
        __syncthreads();
        gload_lds16(tsrc + k0,                      (char*)lT + tid * 16);
        gload_lds16(tsrc + (size_t)32 * 1024 + k0,  (char*)lT + tid * 16 + 4096);
        #pragma unroll
        for (int i = 0; i < 6; ++i)
            gload_lds16(psrc + (size_t)(32 * i) * 1024 + k0, (char*)lP + tid * 16 + i * 4096);
        __syncthreads();   // compiler drains vmcnt(0) before barrier

        #pragma unroll
        for (int kk = 0; kk < 2; ++kk){
            bf16x8 tf[2];
            #pragma unroll
            for (int i = 0; i < 2; ++i){
                int row = wr * 32 + i * 16 + fr;
                int un  = (kk * 4 + fg) ^ (row & 7);
                tf[i] = *(const bf16x8*)((char*)lT + row * 128 + un * 16);
            }
            #pragma unroll
            for (int t = 0; t < 3; ++t){
                #pragma unroll
                for (int j = 0; j < 2; ++j){
                    int row = t * 64 + wc * 32 + j * 16 + fr;
                    int un  = (kk * 4 + fg) ^ (row & 7);
                    bf16x8 pf = *(const bf16x8*)((char*)lP + row * 128 + un * 16);
                    #pragma unroll
                    for (int i = 0; i < 2; ++i)
                        acc[t][i][j] = __builtin_amdgcn_mfma_f32_16x16x32_bf16(pf, tf[i], acc[t][i][j], 0, 0, 0);
                }
            }
        }
    }

    // ---- epilogue: identity correction, F-tile into LDS ------------------
    __syncthreads();
    #pragma unroll
    for (int t = 0; t < 3; ++t)
        #pragma unroll
        for (int i = 0; i < 2; ++i){
            int nl = wr * 32 + i * 16 + fr;        // theta row within tile
            float2 sn = stT[nl];
            #pragma unroll
            for (int j = 0; j < 2; ++j){
                int m0 = t * 64 + wc * 32 + j * 16 + fg * 4;
                us4 pk;
                #pragma unroll
                for (int r = 0; r < 4; ++r){
                    float2 sm = stP[m0 + r];
                    float F = (acc[t][i][j][r] - 512.f * sn.x * sm.x) * sn.y * sm.y * (1.0f / 512.0f);
                    pk[r] = f2bf(F);
                }
                *(us4*)((char*)lF + ((size_t)nl * 200 + m0) * 2) = pk;
            }
        }
    __syncthreads();

    // ---- mask head (proven): rows = wave*16 + (0..15) ---------------------
    f32x4 macc[4];
    #pragma unroll
    for (int j = 0; j < 4; ++j) macc[j] = zero;
    #pragma unroll
    for (int kk = 0; kk < 6; ++kk){
        bf16x8 af = *(const bf16x8*)((char*)lF + ((size_t)(wave * 16 + fr) * 200 + kk * 32 + fg * 8) * 2);
        #pragma unroll
        for (int j = 0; j < 4; ++j){
            bf16x8 bfv = *(const bf16x8*)(w1b + (size_t)(j * 16 + fr) * HW_N + kk * 32 + fg * 8);
            macc[j] = __builtin_amdgcn_mfma_f32_16x16x32_bf16(af, bfv, macc[j], 0, 0, 0);
        }
    }
    float sc[4], sh[4], bb[4], w2v[4];
    #pragma unroll
    for (int j = 0; j < 4; ++j){
        int o = j * 16 + fr;
        float s = bng[o] * rsqrtf(bnv[o] + 1e-5f);
        sc[j] = s;
        sh[j] = bnb[o] - bnm[o] * s;
        bb[j] = m1b[o];
        w2v[j] = m2w[o];
    }
    float mb2 = m2b[0];
    #pragma unroll
    for (int r = 0; r < 4; ++r){
        float y = 0.f;
        #pragma unroll
        for (int j = 0; j < 4; ++j){
            float t = fmaxf((macc[j][r] + bb[j]) * sc[j] + sh[j], 0.f);
            y += t * w2v[j];
        }
        y += __shfl_xor(y, 1);
        y += __shfl_xor(y, 2);
        y += __shfl_xor(y, 4);
        y += __shfl_xor(y, 8);
        if (fr == 0)
            mask[(size_t)b * HW_N + tn * 64 + wave * 16 + fg * 4 + r] =
                1.f + 1.f / (1.f + __expf(-(y + mb2)));   // store (1 + sigmoid)
    }
}

// ---- apply: out = x * mask1p  (mask1p = 1 + sigmoid) ----------------------
__global__ __launch_bounds__(256) void k_apply(const float* __restrict__ x,
                                               const float* __restrict__ mask,
                                               float* __restrict__ out){
    size_t i4 = (size_t)blockIdx.x * 256 + threadIdx.x;
    size_t e  = i4 * 4;
    float4 v = ((const float4*)x)[i4];
    size_t n = e % HW_N;                        // 192 % 4 == 0: same row for all 4
    size_t b = e / ((size_t)C_N * HW_N);
    const float* mk = mask + b * HW_N + n;
    float4 o;
    o.x = v.x * mk[0];
    o.y = v.y * mk[1];
    o.z = v.z * mk[2];
    o.w = v.w * mk[3];
    ((float4*)out)[i4] = o;
}

extern "C" void kernel_launch(void* const* d_in, const int* in_sizes, int n_in,
                              void* d_out, int out_size, void* d_ws, size_t ws_size,
                              hipStream_t stream){
    (void)in_sizes; (void)n_in; (void)out_size; (void)ws_size;
    const float* x   = (const float*)d_in[0];
    const float* tw  = (const float*)d_in[1];
    const float* tb  = (const float*)d_in[2];
    const float* pw  = (const float*)d_in[3];
    const float* pb  = (const float*)d_in[4];
    const float* m1w = (const float*)d_in[5];
    const float* m1b = (const float*)d_in[6];
    const float* bng = (const float*)d_in[7];
    const float* bnb = (const float*)d_in[8];
    const float* bnm = (const float*)d_in[9];
    const float* bnv = (const float*)d_in[10];
    const float* m2w = (const float*)d_in[11];
    const float* m2b = (const float*)d_in[12];
    float* out = (float*)d_out;

    char* ws = (char*)d_ws;
    size_t off = 0;
    unsigned short* xbT = (unsigned short*)(ws + off); off += (size_t)MROWS * C_N * 2;        // 48 MB
    unsigned short* Wc  = (unsigned short*)(ws + off); off += (size_t)1024 * 1024 * 2;        // 2 MB
    float* bias         = (float*)(ws + off);          off += 4096;
    unsigned short* TPt = (unsigned short*)(ws + off); off += (size_t)MROWS * 1024 * 2;       // 48 MB
    float* mask         = (float*)(ws + off);          off += (size_t)MROWS * 4;
    unsigned short* w1b = (unsigned short*)(ws + off); off += (size_t)64 * HW_N * 2;
    off = (off + 255) & ~(size_t)255;
    float2* part        = (float2*)(ws + off);         off += (size_t)MROWS * 16 * 8;         // 3 MB

    k_prep<<<dim3(6, 16, B_N), 256, 0, stream>>>(x, xbT, tw, tb, pw, pb, m1w, Wc, bias, w1b);
    k_gemm1<<<dim3(1536), 256, 0, stream>>>(Wc, bias, xbT, TPt, part);
    k_gemm2m<<<dim3(3, B_N), 256, 0, stream>>>(TPt, part, w1b, m1b, bng, bnb, bnm, bnv, m2w, m2b, mask);
    k_apply<<<dim3(MROWS * C_N / 4 / 256), 256, 0, stream>>>(x, mask, out);
}

// Round 11
// 138.645 us; speedup vs baseline: 1.2907x; 1.0446x over previous
//
#include <hip/hip_runtime.h>

#define B_N 128
#define C_N 1024
#define HW_N 192
#define CI_N 512
#define MROWS (B_N * HW_N)   // 24576 flat rows

typedef short bf16x8 __attribute__((ext_vector_type(8)));
typedef float f32x4 __attribute__((ext_vector_type(4)));
typedef unsigned short us4 __attribute__((ext_vector_type(4)));
typedef unsigned short us8 __attribute__((ext_vector_type(8)));

__device__ __forceinline__ unsigned short f2bf(float f){
    unsigned int u = __builtin_bit_cast(unsigned int, f);
    u += 0x7fffu + ((u >> 16) & 1u);   // round-to-nearest-even
    return (unsigned short)(u >> 16);
}
__device__ __forceinline__ float bf2f(unsigned short h){
    unsigned int u = ((unsigned int)h) << 16;
    return __builtin_bit_cast(float, u);
}
__device__ __forceinline__ void gload_lds16(const void* g, void* l){
    __builtin_amdgcn_global_load_lds(
        (const __attribute__((address_space(1))) unsigned int*)g,
        (__attribute__((address_space(3))) unsigned int*)l, 16, 0, 0);
}

// ---- prep (fused): x transpose->bf16  AND  Wcat/bias/w1 conversion --------
__global__ __launch_bounds__(256) void k_prep(const float* __restrict__ x,
                                              unsigned short* __restrict__ xbT,
                                              const float* __restrict__ tw, const float* __restrict__ tb,
                                              const float* __restrict__ pw, const float* __restrict__ pb,
                                              const float* __restrict__ m1w,
                                              unsigned short* __restrict__ Wc, float* __restrict__ bias,
                                              unsigned short* __restrict__ w1b){
    __shared__ float tile[64][37];
    int b  = blockIdx.z;
    int c0 = blockIdx.y * 64;
    int n0 = blockIdx.x * 32;
    int t  = threadIdx.x;

    int fid = ((blockIdx.z * gridDim.y + blockIdx.y) * gridDim.x + blockIdx.x) * 256 + t;
    if (fid < 1024 * 1024){
        int o = fid >> 10, c = fid & 1023;
        float v = (o < 512) ? tw[(size_t)o * 1024 + c] : pw[(size_t)(o - 512) * 1024 + c];
        Wc[fid] = f2bf(v);
        if (fid < 1024) bias[fid] = (fid < 512) ? tb[fid] : pb[fid - 512];
        if (fid < 64 * HW_N) w1b[fid] = f2bf(m1w[fid]);
    }

    const float* xp = x + (size_t)b * C_N * HW_N;
    int cr = t >> 3;          // 0..31
    int nw = (t & 7) * 4;     // 0..28
    #pragma unroll
    for (int i = 0; i < 2; ++i){
        float4 v = *(const float4*)(xp + (size_t)(c0 + cr + 32 * i) * HW_N + n0 + nw);
        tile[cr + 32 * i][nw + 0] = v.x;
        tile[cr + 32 * i][nw + 1] = v.y;
        tile[cr + 32 * i][nw + 2] = v.z;
        tile[cr + 32 * i][nw + 3] = v.w;
    }
    __syncthreads();
    int nl = t >> 3;          // 0..31 output row (n)
    int j  = t & 7;           // 8-elem c group
    us8 pk;
    #pragma unroll
    for (int e = 0; e < 8; ++e)
        pk[e] = f2bf(tile[j * 8 + e][nl]);
    *(us8*)(xbT + (size_t)(b * HW_N + n0 + nl) * C_N + c0 + j * 8) = pk;
}

// ---- GEMM1 (R4 proven: 128x128, BK=64, XCD-remapped, 2-barrier m97) -------
__global__ __launch_bounds__(256, 3) void k_gemm1(const unsigned short* __restrict__ Wc,
                                               const float* __restrict__ bias,
                                               const unsigned short* __restrict__ xbT,
                                               unsigned short* __restrict__ TPt,
                                               float2* __restrict__ part){
    __shared__ __align__(16) unsigned short lW[128 * 64];  // 16KB, rows = o
    __shared__ __align__(16) unsigned short lX[128 * 64];  // 16KB, rows = n
    int bid  = blockIdx.x;
    int xcd  = bid & 7;
    int slot = bid >> 3;
    int mb = xcd * 24 + (slot >> 3);   // n-tile (0..191)
    int nb = slot & 7;                 // o-tile (0..7)
    int tid = threadIdx.x, lane = tid & 63, wave = tid >> 6;
    int wr = wave >> 1, wc = wave & 1;
    int fr = lane & 15, fg = lane >> 4;

    const unsigned short* Wg = Wc  + (size_t)(nb * 128) * C_N;
    const unsigned short* Xg = xbT + (size_t)(mb * 128) * C_N;

    int row0 = tid >> 3;                 // 0..31
    int su   = tid & 7;
    int gsw  = (su ^ (row0 & 7)) * 8;    // pre-swizzled global col (elems)
    const unsigned short* wsrc = Wg + (size_t)row0 * C_N + gsw;
    const unsigned short* xsrc = Xg + (size_t)row0 * C_N + gsw;

    f32x4 acc[4][4];
    f32x4 zero = {0.f, 0.f, 0.f, 0.f};
    #pragma unroll
    for (int i = 0; i < 4; ++i)
        #pragma unroll
        for (int j = 0; j < 4; ++j)
            acc[i][j] = zero;

    for (int k0 = 0; k0 < C_N; k0 += 64){
        __syncthreads();
        #pragma unroll
        for (int i = 0; i < 4; ++i){
            gload_lds16(wsrc + (size_t)(32 * i) * C_N + k0, (char*)lW + tid * 16 + i * 4096);
            gload_lds16(xsrc + (size_t)(32 * i) * C_N + k0, (char*)lX + tid * 16 + i * 4096);
        }
        __syncthreads();   // compiler drains vmcnt(0) here (m97 structure)

        #pragma unroll
        for (int kk = 0; kk < 2; ++kk){
            bf16x8 wf[4], xf[4];
            #pragma unroll
            for (int j = 0; j < 4; ++j){
                int row = wc * 64 + j * 16 + fr;
                int un  = (kk * 4 + fg) ^ (row & 7);
                wf[j] = *(const bf16x8*)((char*)lW + row * 128 + un * 16);
            }
            #pragma unroll
            for (int i = 0; i < 4; ++i){
                int row = wr * 64 + i * 16 + fr;
                int un  = (kk * 4 + fg) ^ (row & 7);
                xf[i] = *(const bf16x8*)((char*)lX + row * 128 + un * 16);
            }
            #pragma unroll
            for (int i = 0; i < 4; ++i)
                #pragma unroll
                for (int j = 0; j < 4; ++j)
                    acc[i][j] = __builtin_amdgcn_mfma_f32_16x16x32_bf16(wf[j], xf[i], acc[i][j], 0, 0, 0);
        }
    }

    // epilogue: D[row=o (fg*4+r within frag j), col=n (fr within frag i)]
    float s[4] = {0.f,0.f,0.f,0.f}, q[4] = {0.f,0.f,0.f,0.f};
    #pragma unroll
    for (int i = 0; i < 4; ++i){
        int n = mb * 128 + wr * 64 + i * 16 + fr;
        #pragma unroll
        for (int j = 0; j < 4; ++j){
            int o0 = nb * 128 + wc * 64 + j * 16 + fg * 4;
            float4 b4 = *(const float4*)(bias + o0);
            float v0 = acc[i][j][0] + b4.x;
            float v1 = acc[i][j][1] + b4.y;
            float v2 = acc[i][j][2] + b4.z;
            float v3 = acc[i][j][3] + b4.w;
            s[i] += v0 + v1 + v2 + v3;
            q[i] += v0*v0 + v1*v1 + v2*v2 + v3*v3;
            us4 pk;
            pk[0] = f2bf(v0); pk[1] = f2bf(v1); pk[2] = f2bf(v2); pk[3] = f2bf(v3);
            *(us4*)(TPt + (size_t)n * 1024 + o0) = pk;
        }
    }
    #pragma unroll
    for (int i = 0; i < 4; ++i){
        s[i] += __shfl_xor(s[i], 16); s[i] += __shfl_xor(s[i], 32);
        q[i] += __shfl_xor(q[i], 16); q[i] += __shfl_xor(q[i], 32);
    }
    if (lane < 16){   // fg == 0
        int chunk = nb * 2 + wc;   // 64-col chunk index (0..15)
        #pragma unroll
        for (int i = 0; i < 4; ++i){
            int n = mb * 128 + wr * 64 + i * 16 + fr;
            part[(size_t)n * 16 + chunk] = make_float2(s[i], q[i]);
        }
    }
}

// ---- GEMM2 (raw, covariance identity) + stats-fold + mask head fused ------
// XCD-aware decode: all 3 tn-blocks of a batch b land on XCD b&7 consecutively
// -> phi panel (192KB) fetched from HBM once, L2-hit for the other two.
__global__ __launch_bounds__(256) void k_gemm2m(const unsigned short* __restrict__ TPt,
        const float2* __restrict__ part,
        const unsigned short* __restrict__ w1b, const float* __restrict__ m1b,
        const float* __restrict__ bng, const float* __restrict__ bnb,
        const float* __restrict__ bnm, const float* __restrict__ bnv,
        const float* __restrict__ m2w, const float* __restrict__ m2b,
        float* __restrict__ mask){
    __shared__ __align__(16) unsigned short lT[64 * 64];    // 8KB  theta (raw)
    __shared__ __align__(16) unsigned short lP[192 * 64];   // 24KB phi (raw)
    __shared__ __align__(16) unsigned short lF[64 * 200];   // 25.6KB F-tile (pad 200)
    __shared__ float2 stT[64];
    __shared__ float2 stP[192];
    int bid  = blockIdx.x;
    int xcd  = bid & 7;
    int slot = bid >> 3;        // 0..47
    int tn   = slot % 3;        // theta 64-row panel (0..2)
    int b    = (slot / 3) * 8 + xcd;   // bijective; same-b blocks share an XCD
    int tid = threadIdx.x, lane = tid & 63, wave = tid >> 6;
    int wr = wave >> 1, wc = wave & 1;
    int fr = lane & 15, fg = lane >> 4;

    // ---- stats fold: thread<64 -> theta row, others -> phi rows 0..191 ----
    {
        const float2* pp;
        if (tid < 64)
            pp = part + (size_t)(b * HW_N + tn * 64 + tid) * 16;        // theta chunks 0..7
        else
            pp = part + (size_t)(b * HW_N + (tid - 64)) * 16 + 8;       // phi chunks 8..15
        float S = 0.f, Q = 0.f;
        #pragma unroll
        for (int k = 0; k < 8; ++k){ float2 v = pp[k]; S += v.x; Q += v.y; }
        float mean = S * (1.f / 512.f);
        float var  = (Q - 512.f * mean * mean) * (1.f / 511.f);
        float2 r = make_float2(mean, 1.f / (sqrtf(fmaxf(var, 0.f)) + 1e-4f));
        if (tid < 64) stT[tid] = r; else stP[tid - 64] = r;
    }
    // (first K-loop barrier orders these stores before epilogue reads)

    // ---- staging setup (rule 21: pre-swizzled global src, swizzled read) --
    int row0 = tid >> 3;                 // 0..31
    int su   = tid & 7;
    int gsw  = (su ^ (row0 & 7)) * 8;    // (row0+32i)&7 == row0&7
    const unsigned short* tsrc = TPt + (size_t)(b * HW_N + tn * 64 + row0) * 1024 + gsw;
    const unsigned short* psrc = TPt + (size_t)(b * HW_N + row0) * 1024 + 512 + gsw;

    f32x4 acc[3][2][2];
    f32x4 zero = {0.f, 0.f, 0.f, 0.f};
    #pragma unroll
    for (int t = 0; t < 3; ++t)
        #pragma unroll
        for (int i = 0; i < 2; ++i)
            #pragma unroll
            for (int j = 0; j < 2; ++j)
                acc[t][i][j] = zero;

    for (int k0 = 0; k0 < CI_N; k0 += 64){
        __syncthreads();
        gload_lds16(tsrc + k0,                      (char*)lT + tid * 16);
        gload_lds16(tsrc + (size_t)32 * 1024 + k0,  (char*)lT + tid * 16 + 4096);
        #pragma unroll
        for (int i = 0; i < 6; ++i)
            gload_lds16(psrc + (size_t)(32 * i) * 1024 + k0, (char*)lP + tid * 16 + i * 4096);
        __syncthreads();   // compiler drains vmcnt(0) before barrier

        #pragma unroll
        for (int kk = 0; kk < 2; ++kk){
            bf16x8 tf[2];
            #pragma unroll
            for (int i = 0; i < 2; ++i){
                int row = wr * 32 + i * 16 + fr;
                int un  = (kk * 4 + fg) ^ (row & 7);
                tf[i] = *(const bf16x8*)((char*)lT + row * 128 + un * 16);
            }
            #pragma unroll
            for (int t = 0; t < 3; ++t){
                #pragma unroll
                for (int j = 0; j < 2; ++j){
                    int row = t * 64 + wc * 32 + j * 16 + fr;
                    int un  = (kk * 4 + fg) ^ (row & 7);
                    bf16x8 pf = *(const bf16x8*)((char*)lP + row * 128 + un * 16);
                    #pragma unroll
                    for (int i = 0; i < 2; ++i)
                        acc[t][i][j] = __builtin_amdgcn_mfma_f32_16x16x32_bf16(pf, tf[i], acc[t][i][j], 0, 0, 0);
                }
            }
        }
    }

    // ---- epilogue: identity correction, F-tile into LDS ------------------
    __syncthreads();
    #pragma unroll
    for (int t = 0; t < 3; ++t)
        #pragma unroll
        for (int i = 0; i < 2; ++i){
            int nl = wr * 32 + i * 16 + fr;        // theta row within tile
            float2 sn = stT[nl];
            #pragma unroll
            for (int j = 0; j < 2; ++j){
                int m0 = t * 64 + wc * 32 + j * 16 + fg * 4;
                us4 pk;
                #pragma unroll
                for (int r = 0; r < 4; ++r){
                    float2 sm = stP[m0 + r];
                    float F = (acc[t][i][j][r] - 512.f * sn.x * sm.x) * sn.y * sm.y * (1.0f / 512.0f);
                    pk[r] = f2bf(F);
                }
                *(us4*)((char*)lF + ((size_t)nl * 200 + m0) * 2) = pk;
            }
        }
    __syncthreads();

    // ---- mask head (proven): rows = wave*16 + (0..15) ---------------------
    f32x4 macc[4];
    #pragma unroll
    for (int j = 0; j < 4; ++j) macc[j] = zero;
    #pragma unroll
    for (int kk = 0; kk < 6; ++kk){
        bf16x8 af = *(const bf16x8*)((char*)lF + ((size_t)(wave * 16 + fr) * 200 + kk * 32 + fg * 8) * 2);
        #pragma unroll
        for (int j = 0; j < 4; ++j){
            bf16x8 bfv = *(const bf16x8*)(w1b + (size_t)(j * 16 + fr) * HW_N + kk * 32 + fg * 8);
            macc[j] = __builtin_amdgcn_mfma_f32_16x16x32_bf16(af, bfv, macc[j], 0, 0, 0);
        }
    }
    float sc[4], sh[4], bb[4], w2v[4];
    #pragma unroll
    for (int j = 0; j < 4; ++j){
        int o = j * 16 + fr;
        float s = bng[o] * rsqrtf(bnv[o] + 1e-5f);
        sc[j] = s;
        sh[j] = bnb[o] - bnm[o] * s;
        bb[j] = m1b[o];
        w2v[j] = m2w[o];
    }
    float mb2 = m2b[0];
    #pragma unroll
    for (int r = 0; r < 4; ++r){
        float y = 0.f;
        #pragma unroll
        for (int j = 0; j < 4; ++j){
            float t = fmaxf((macc[j][r] + bb[j]) * sc[j] + sh[j], 0.f);
            y += t * w2v[j];
        }
        y += __shfl_xor(y, 1);
        y += __shfl_xor(y, 2);
        y += __shfl_xor(y, 4);
        y += __shfl_xor(y, 8);
        if (fr == 0)
            mask[(size_t)b * HW_N + tn * 64 + wave * 16 + fg * 4 + r] =
                1.f + 1.f / (1.f + __expf(-(y + mb2)));   // store (1 + sigmoid)
    }
}

// ---- apply: out = x * mask1p  (mask1p = 1 + sigmoid) ----------------------
__global__ __launch_bounds__(256) void k_apply(const float* __restrict__ x,
                                               const float* __restrict__ mask,
                                               float* __restrict__ out){
    size_t i4 = (size_t)blockIdx.x * 256 + threadIdx.x;
    size_t e  = i4 * 4;
    float4 v = ((const float4*)x)[i4];
    size_t n = e % HW_N;                        // 192 % 4 == 0: same row for all 4
    size_t b = e / ((size_t)C_N * HW_N);
    const float* mk = mask + b * HW_N + n;
    float4 o;
    o.x = v.x * mk[0];
    o.y = v.y * mk[1];
    o.z = v.z * mk[2];
    o.w = v.w * mk[3];
    ((float4*)out)[i4] = o;
}

extern "C" void kernel_launch(void* const* d_in, const int* in_sizes, int n_in,
                              void* d_out, int out_size, void* d_ws, size_t ws_size,
                              hipStream_t stream){
    (void)in_sizes; (void)n_in; (void)out_size; (void)ws_size;
    const float* x   = (const float*)d_in[0];
    const float* tw  = (const float*)d_in[1];
    const float* tb  = (const float*)d_in[2];
    const float* pw  = (const float*)d_in[3];
    const float* pb  = (const float*)d_in[4];
    const float* m1w = (const float*)d_in[5];
    const float* m1b = (const float*)d_in[6];
    const float* bng = (const float*)d_in[7];
    const float* bnb = (const float*)d_in[8];
    const float* bnm = (const float*)d_in[9];
    const float* bnv = (const float*)d_in[10];
    const float* m2w = (const float*)d_in[11];
    const float* m2b = (const float*)d_in[12];
    float* out = (float*)d_out;

    char* ws = (char*)d_ws;
    size_t off = 0;
    unsigned short* xbT = (unsigned short*)(ws + off); off += (size_t)MROWS * C_N * 2;        // 48 MB
    unsigned short* Wc  = (unsigned short*)(ws + off); off += (size_t)1024 * 1024 * 2;        // 2 MB
    float* bias         = (float*)(ws + off);          off += 4096;
    unsigned short* TPt = (unsigned short*)(ws + off); off += (size_t)MROWS * 1024 * 2;       // 48 MB
    float* mask         = (float*)(ws + off);          off += (size_t)MROWS * 4;
    unsigned short* w1b = (unsigned short*)(ws + off); off += (size_t)64 * HW_N * 2;
    off = (off + 255) & ~(size_t)255;
    float2* part        = (float2*)(ws + off);         off += (size_t)MROWS * 16 * 8;         // 3 MB

    k_prep<<<dim3(6, 16, B_N), 256, 0, stream>>>(x, xbT, tw, tb, pw, pb, m1w, Wc, bias, w1b);
    k_gemm1<<<dim3(1536), 256, 0, stream>>>(Wc, bias, xbT, TPt, part);
    k_gemm2m<<<dim3(384), 256, 0, stream>>>(TPt, part, w1b, m1b, bng, bnb, bnm, bnv, m2w, m2b, mask);
    k_apply<<<dim3(MROWS * C_N / 4 / 256), 256, 0, stream>>>(x, mask, out);
}

// Round 12
// 138.624 us; speedup vs baseline: 1.2909x; 1.0001x over previous
//
#include <hip/hip_runtime.h>

#define B_N 128
#define C_N 1024
#define HW_N 192
#define CI_N 512
#define MROWS (B_N * HW_N)   // 24576 flat rows

typedef short bf16x8 __attribute__((ext_vector_type(8)));
typedef float f32x4 __attribute__((ext_vector_type(4)));
typedef unsigned short us4 __attribute__((ext_vector_type(4)));
typedef unsigned short us8 __attribute__((ext_vector_type(8)));

__device__ __forceinline__ unsigned short f2bf(float f){
    unsigned int u = __builtin_bit_cast(unsigned int, f);
    u += 0x7fffu + ((u >> 16) & 1u);   // round-to-nearest-even
    return (unsigned short)(u >> 16);
}
__device__ __forceinline__ float bf2f(unsigned short h){
    unsigned int u = ((unsigned int)h) << 16;
    return __builtin_bit_cast(float, u);
}
__device__ __forceinline__ void gload_lds16(const void* g, void* l){
    __builtin_amdgcn_global_load_lds(
        (const __attribute__((address_space(1))) unsigned int*)g,
        (__attribute__((address_space(3))) unsigned int*)l, 16, 0, 0);
}

// ---- prep (fused): x transpose->bf16  AND  Wcat/bias/w1 conversion --------
__global__ __launch_bounds__(256) void k_prep(const float* __restrict__ x,
                                              unsigned short* __restrict__ xbT,
                                              const float* __restrict__ tw, const float* __restrict__ tb,
                                              const float* __restrict__ pw, const float* __restrict__ pb,
                                              const float* __restrict__ m1w,
                                              unsigned short* __restrict__ Wc, float* __restrict__ bias,
                                              unsigned short* __restrict__ w1b){
    __shared__ float tile[64][37];
    int b  = blockIdx.z;
    int c0 = blockIdx.y * 64;
    int n0 = blockIdx.x * 32;
    int t  = threadIdx.x;

    int fid = ((blockIdx.z * gridDim.y + blockIdx.y) * gridDim.x + blockIdx.x) * 256 + t;
    if (fid < 1024 * 1024){
        int o = fid >> 10, c = fid & 1023;
        float v = (o < 512) ? tw[(size_t)o * 1024 + c] : pw[(size_t)(o - 512) * 1024 + c];
        Wc[fid] = f2bf(v);
        if (fid < 1024) bias[fid] = (fid < 512) ? tb[fid] : pb[fid - 512];
        if (fid < 64 * HW_N) w1b[fid] = f2bf(m1w[fid]);
    }

    const float* xp = x + (size_t)b * C_N * HW_N;
    int cr = t >> 3;          // 0..31
    int nw = (t & 7) * 4;     // 0..28
    #pragma unroll
    for (int i = 0; i < 2; ++i){
        float4 v = *(const float4*)(xp + (size_t)(c0 + cr + 32 * i) * HW_N + n0 + nw);
        tile[cr + 32 * i][nw + 0] = v.x;
        tile[cr + 32 * i][nw + 1] = v.y;
        tile[cr + 32 * i][nw + 2] = v.z;
        tile[cr + 32 * i][nw + 3] = v.w;
    }
    __syncthreads();
    int nl = t >> 3;          // 0..31 output row (n)
    int j  = t & 7;           // 8-elem c group
    us8 pk;
    #pragma unroll
    for (int e = 0; e < 8; ++e)
        pk[e] = f2bf(tile[j * 8 + e][nl]);
    *(us8*)(xbT + (size_t)(b * HW_N + n0 + nl) * C_N + c0 + j * 8) = pk;
}

// ---- GEMM1 (R4 proven: 128x128, BK=64, XCD-remapped, 2-barrier m97) -------
__global__ __launch_bounds__(256, 3) void k_gemm1(const unsigned short* __restrict__ Wc,
                                               const float* __restrict__ bias,
                                               const unsigned short* __restrict__ xbT,
                                               unsigned short* __restrict__ TPt,
                                               float2* __restrict__ part){
    __shared__ __align__(16) unsigned short lW[128 * 64];  // 16KB, rows = o
    __shared__ __align__(16) unsigned short lX[128 * 64];  // 16KB, rows = n
    int bid  = blockIdx.x;
    int xcd  = bid & 7;
    int slot = bid >> 3;
    int mb = xcd * 24 + (slot >> 3);   // n-tile (0..191)
    int nb = slot & 7;                 // o-tile (0..7)
    int tid = threadIdx.x, lane = tid & 63, wave = tid >> 6;
    int wr = wave >> 1, wc = wave & 1;
    int fr = lane & 15, fg = lane >> 4;

    const unsigned short* Wg = Wc  + (size_t)(nb * 128) * C_N;
    const unsigned short* Xg = xbT + (size_t)(mb * 128) * C_N;

    int row0 = tid >> 3;                 // 0..31
    int su   = tid & 7;
    int gsw  = (su ^ (row0 & 7)) * 8;    // pre-swizzled global col (elems)
    const unsigned short* wsrc = Wg + (size_t)row0 * C_N + gsw;
    const unsigned short* xsrc = Xg + (size_t)row0 * C_N + gsw;

    f32x4 acc[4][4];
    f32x4 zero = {0.f, 0.f, 0.f, 0.f};
    #pragma unroll
    for (int i = 0; i < 4; ++i)
        #pragma unroll
        for (int j = 0; j < 4; ++j)
            acc[i][j] = zero;

    for (int k0 = 0; k0 < C_N; k0 += 64){
        __syncthreads();
        #pragma unroll
        for (int i = 0; i < 4; ++i){
            gload_lds16(wsrc + (size_t)(32 * i) * C_N + k0, (char*)lW + tid * 16 + i * 4096);
            gload_lds16(xsrc + (size_t)(32 * i) * C_N + k0, (char*)lX + tid * 16 + i * 4096);
        }
        __syncthreads();   // compiler drains vmcnt(0) here (m97 structure)

        #pragma unroll
        for (int kk = 0; kk < 2; ++kk){
            bf16x8 wf[4], xf[4];
            #pragma unroll
            for (int j = 0; j < 4; ++j){
                int row = wc * 64 + j * 16 + fr;
                int un  = (kk * 4 + fg) ^ (row & 7);
                wf[j] = *(const bf16x8*)((char*)lW + row * 128 + un * 16);
            }
            #pragma unroll
            for (int i = 0; i < 4; ++i){
                int row = wr * 64 + i * 16 + fr;
                int un  = (kk * 4 + fg) ^ (row & 7);
                xf[i] = *(const bf16x8*)((char*)lX + row * 128 + un * 16);
            }
            #pragma unroll
            for (int i = 0; i < 4; ++i)
                #pragma unroll
                for (int j = 0; j < 4; ++j)
                    acc[i][j] = __builtin_amdgcn_mfma_f32_16x16x32_bf16(wf[j], xf[i], acc[i][j], 0, 0, 0);
        }
    }

    // epilogue: D[row=o (fg*4+r within frag j), col=n (fr within frag i)]
    float s[4] = {0.f,0.f,0.f,0.f}, q[4] = {0.f,0.f,0.f,0.f};
    #pragma unroll
    for (int i = 0; i < 4; ++i){
        int n = mb * 128 + wr * 64 + i * 16 + fr;
        #pragma unroll
        for (int j = 0; j < 4; ++j){
            int o0 = nb * 128 + wc * 64 + j * 16 + fg * 4;
            float4 b4 = *(const float4*)(bias + o0);
            float v0 = acc[i][j][0] + b4.x;
            float v1 = acc[i][j][1] + b4.y;
            float v2 = acc[i][j][2] + b4.z;
            float v3 = acc[i][j][3] + b4.w;
            s[i] += v0 + v1 + v2 + v3;
            q[i] += v0*v0 + v1*v1 + v2*v2 + v3*v3;
            us4 pk;
            pk[0] = f2bf(v0); pk[1] = f2bf(v1); pk[2] = f2bf(v2); pk[3] = f2bf(v3);
            *(us4*)(TPt + (size_t)n * 1024 + o0) = pk;
        }
    }
    #pragma unroll
    for (int i = 0; i < 4; ++i){
        s[i] += __shfl_xor(s[i], 16); s[i] += __shfl_xor(s[i], 32);
        q[i] += __shfl_xor(q[i], 16); q[i] += __shfl_xor(q[i], 32);
    }
    if (lane < 16){   // fg == 0
        int chunk = nb * 2 + wc;   // 64-col chunk index (0..15)
        #pragma unroll
        for (int i = 0; i < 4; ++i){
            int n = mb * 128 + wr * 64 + i * 16 + fr;
            part[(size_t)n * 16 + chunk] = make_float2(s[i], q[i]);
        }
    }
}

// ---- GEMM2 (raw, covariance identity) + stats-fold + mask head fused ------
// XCD-aware decode: all 3 tn-blocks of a batch b land on XCD b&7 consecutively
// -> phi panel (192KB) fetched from HBM once, L2-hit for the other two.
__global__ __launch_bounds__(256) void k_gemm2m(const unsigned short* __restrict__ TPt,
        const float2* __restrict__ part,
        const unsigned short* __restrict__ w1b, const float* __restrict__ m1b,
        const float* __restrict__ bng, const float* __restrict__ bnb,
        const float* __restrict__ bnm, const float* __restrict__ bnv,
        const float* __restrict__ m2w, const float* __restrict__ m2b,
        float* __restrict__ mask){
    __shared__ __align__(16) unsigned short lT[64 * 64];    // 8KB  theta (raw)
    __shared__ __align__(16) unsigned short lP[192 * 64];   // 24KB phi (raw)
    __shared__ __align__(16) unsigned short lF[64 * 200];   // 25.6KB F-tile (pad 200)
    __shared__ float2 stT[64];
    __shared__ float2 stP[192];
    int bid  = blockIdx.x;
    int xcd  = bid & 7;
    int slot = bid >> 3;        // 0..47
    int tn   = slot % 3;        // theta 64-row panel (0..2)
    int b    = (slot / 3) * 8 + xcd;   // bijective; same-b blocks share an XCD
    int tid = threadIdx.x, lane = tid & 63, wave = tid >> 6;
    int wr = wave >> 1, wc = wave & 1;
    int fr = lane & 15, fg = lane >> 4;

    // ---- stats fold: thread<64 -> theta row, others -> phi rows 0..191 ----
    {
        const float2* pp;
        if (tid < 64)
            pp = part + (size_t)(b * HW_N + tn * 64 + tid) * 16;        // theta chunks 0..7
        else
            pp = part + (size_t)(b * HW_N + (tid - 64)) * 16 + 8;       // phi chunks 8..15
        float S = 0.f, Q = 0.f;
        #pragma unroll
        for (int k = 0; k < 8; ++k){ float2 v = pp[k]; S += v.x; Q += v.y; }
        float mean = S * (1.f / 512.f);
        float var  = (Q - 512.f * mean * mean) * (1.f / 511.f);
        float2 r = make_float2(mean, 1.f / (sqrtf(fmaxf(var, 0.f)) + 1e-4f));
        if (tid < 64) stT[tid] = r; else stP[tid - 64] = r;
    }
    // (first K-loop barrier orders these stores before epilogue reads)

    // ---- staging setup (rule 21: pre-swizzled global src, swizzled read) --
    int row0 = tid >> 3;                 // 0..31
    int su   = tid & 7;
    int gsw  = (su ^ (row0 & 7)) * 8;    // (row0+32i)&7 == row0&7
    const unsigned short* tsrc = TPt + (size_t)(b * HW_N + tn * 64 + row0) * 1024 + gsw;
    const unsigned short* psrc = TPt + (size_t)(b * HW_N + row0) * 1024 + 512 + gsw;

    f32x4 acc[3][2][2];
    f32x4 zero = {0.f, 0.f, 0.f, 0.f};
    #pragma unroll
    for (int t = 0; t < 3; ++t)
        #pragma unroll
        for (int i = 0; i < 2; ++i)
            #pragma unroll
            for (int j = 0; j < 2; ++j)
                acc[t][i][j] = zero;

    for (int k0 = 0; k0 < CI_N; k0 += 64){
        __syncthreads();
        gload_lds16(tsrc + k0,                      (char*)lT + tid * 16);
        gload_lds16(tsrc + (size_t)32 * 1024 + k0,  (char*)lT + tid * 16 + 4096);
        #pragma unroll
        for (int i = 0; i < 6; ++i)
            gload_lds16(psrc + (size_t)(32 * i) * 1024 + k0, (char*)lP + tid * 16 + i * 4096);
        __syncthreads();   // compiler drains vmcnt(0) before barrier

        #pragma unroll
        for (int kk = 0; kk < 2; ++kk){
            bf16x8 tf[2];
            #pragma unroll
            for (int i = 0; i < 2; ++i){
                int row = wr * 32 + i * 16 + fr;
                int un  = (kk * 4 + fg) ^ (row & 7);
                tf[i] = *(const bf16x8*)((char*)lT + row * 128 + un * 16);
            }
            #pragma unroll
            for (int t = 0; t < 3; ++t){
                #pragma unroll
                for (int j = 0; j < 2; ++j){
                    int row = t * 64 + wc * 32 + j * 16 + fr;
                    int un  = (kk * 4 + fg) ^ (row & 7);
                    bf16x8 pf = *(const bf16x8*)((char*)lP + row * 128 + un * 16);
                    #pragma unroll
                    for (int i = 0; i < 2; ++i)
                        acc[t][i][j] = __builtin_amdgcn_mfma_f32_16x16x32_bf16(pf, tf[i], acc[t][i][j], 0, 0, 0);
                }
            }
        }
    }

    // ---- epilogue: identity correction, F-tile into LDS ------------------
    __syncthreads();
    #pragma unroll
    for (int t = 0; t < 3; ++t)
        #pragma unroll
        for (int i = 0; i < 2; ++i){
            int nl = wr * 32 + i * 16 + fr;        // theta row within tile
            float2 sn = stT[nl];
            #pragma unroll
            for (int j = 0; j < 2; ++j){
                int m0 = t * 64 + wc * 32 + j * 16 + fg * 4;
                us4 pk;
                #pragma unroll
                for (int r = 0; r < 4; ++r){
                    float2 sm = stP[m0 + r];
                    float F = (acc[t][i][j][r] - 512.f * sn.x * sm.x) * sn.y * sm.y * (1.0f / 512.0f);
                    pk[r] = f2bf(F);
                }
                *(us4*)((char*)lF + ((size_t)nl * 200 + m0) * 2) = pk;
            }
        }
    __syncthreads();

    // ---- mask head (proven): rows = wave*16 + (0..15) ---------------------
    f32x4 macc[4];
    #pragma unroll
    for (int j = 0; j < 4; ++j) macc[j] = zero;
    #pragma unroll
    for (int kk = 0; kk < 6; ++kk){
        bf16x8 af = *(const bf16x8*)((char*)lF + ((size_t)(wave * 16 + fr) * 200 + kk * 32 + fg * 8) * 2);
        #pragma unroll
        for (int j = 0; j < 4; ++j){
            bf16x8 bfv = *(const bf16x8*)(w1b + (size_t)(j * 16 + fr) * HW_N + kk * 32 + fg * 8);
            macc[j] = __builtin_amdgcn_mfma_f32_16x16x32_bf16(af, bfv, macc[j], 0, 0, 0);
        }
    }
    float sc[4], sh[4], bb[4], w2v[4];
    #pragma unroll
    for (int j = 0; j < 4; ++j){
        int o = j * 16 + fr;
        float s = bng[o] * rsqrtf(bnv[o] + 1e-5f);
        sc[j] = s;
        sh[j] = bnb[o] - bnm[o] * s;
        bb[j] = m1b[o];
        w2v[j] = m2w[o];
    }
    float mb2 = m2b[0];
    #pragma unroll
    for (int r = 0; r < 4; ++r){
        float y = 0.f;
        #pragma unroll
        for (int j = 0; j < 4; ++j){
            float t = fmaxf((macc[j][r] + bb[j]) * sc[j] + sh[j], 0.f);
            y += t * w2v[j];
        }
        y += __shfl_xor(y, 1);
        y += __shfl_xor(y, 2);
        y += __shfl_xor(y, 4);
        y += __shfl_xor(y, 8);
        if (fr == 0)
            mask[(size_t)b * HW_N + tn * 64 + wave * 16 + fg * 4 + r] =
                1.f + 1.f / (1.f + __expf(-(y + mb2)));   // store (1 + sigmoid)
    }
}

// ---- apply2: out[b][c][n] = bf2f(xbT[b][n][c]) * mask1p[b][n] --------------
// Reads the bf16 transposed copy (48 MB) instead of fp32 x (96 MB): apply leg
// traffic 192 -> 144 MB. Tile transpose mirrors k_prep (LDS fp32 [64][33]).
__global__ __launch_bounds__(256) void k_apply2(const unsigned short* __restrict__ xbT,
                                                const float* __restrict__ mask,
                                                float* __restrict__ out){
    __shared__ float tile[64][33];
    int b  = blockIdx.z;
    int c0 = blockIdx.y * 64;
    int n0 = blockIdx.x * 32;
    int t  = threadIdx.x;

    // load: thread t -> n-row nl = t>>3, c-group j = t&7 (us8 = 8 c elems)
    int nl = t >> 3;          // 0..31
    int j  = t & 7;
    us8 v = *(const us8*)(xbT + (size_t)(b * HW_N + n0 + nl) * C_N + c0 + j * 8);
    #pragma unroll
    for (int e = 0; e < 8; ++e)
        tile[j * 8 + e][nl] = bf2f((unsigned short)v[e]);
    __syncthreads();

    // store: thread t -> c-row cr = t>>3 (+32), n-quad nw = (t&7)*4
    int cr = t >> 3;          // 0..31
    int nw = (t & 7) * 4;     // 0..28
    float4 mk = *(const float4*)(mask + (size_t)b * HW_N + n0 + nw);
    #pragma unroll
    for (int i = 0; i < 2; ++i){
        int c = c0 + cr + 32 * i;
        float4 o;
        o.x = tile[cr + 32 * i][nw + 0] * mk.x;
        o.y = tile[cr + 32 * i][nw + 1] * mk.y;
        o.z = tile[cr + 32 * i][nw + 2] * mk.z;
        o.w = tile[cr + 32 * i][nw + 3] * mk.w;
        *(float4*)(out + (size_t)(b * C_N + c) * HW_N + n0 + nw) = o;
    }
}

extern "C" void kernel_launch(void* const* d_in, const int* in_sizes, int n_in,
                              void* d_out, int out_size, void* d_ws, size_t ws_size,
                              hipStream_t stream){
    (void)in_sizes; (void)n_in; (void)out_size; (void)ws_size;
    const float* x   = (const float*)d_in[0];
    const float* tw  = (const float*)d_in[1];
    const float* tb  = (const float*)d_in[2];
    const float* pw  = (const float*)d_in[3];
    const float* pb  = (const float*)d_in[4];
    const float* m1w = (const float*)d_in[5];
    const float* m1b = (const float*)d_in[6];
    const float* bng = (const float*)d_in[7];
    const float* bnb = (const float*)d_in[8];
    const float* bnm = (const float*)d_in[9];
    const float* bnv = (const float*)d_in[10];
    const float* m2w = (const float*)d_in[11];
    const float* m2b = (const float*)d_in[12];
    float* out = (float*)d_out;

    char* ws = (char*)d_ws;
    size_t off = 0;
    unsigned short* xbT = (unsigned short*)(ws + off); off += (size_t)MROWS * C_N * 2;        // 48 MB
    unsigned short* Wc  = (unsigned short*)(ws + off); off += (size_t)1024 * 1024 * 2;        // 2 MB
    float* bias         = (float*)(ws + off);          off += 4096;
    unsigned short* TPt = (unsigned short*)(ws + off); off += (size_t)MROWS * 1024 * 2;       // 48 MB
    float* mask         = (float*)(ws + off);          off += (size_t)MROWS * 4;
    unsigned short* w1b = (unsigned short*)(ws + off); off += (size_t)64 * HW_N * 2;
    off = (off + 255) & ~(size_t)255;
    float2* part        = (float2*)(ws + off);         off += (size_t)MROWS * 16 * 8;         // 3 MB

    k_prep<<<dim3(6, 16, B_N), 256, 0, stream>>>(x, xbT, tw, tb, pw, pb, m1w, Wc, bias, w1b);
    k_gemm1<<<dim3(1536), 256, 0, stream>>>(Wc, bias, xbT, TPt, part);
    k_gemm2m<<<dim3(384), 256, 0, stream>>>(TPt, part, w1b, m1b, bng, bnb, bnm, bnv, m2w, m2b, mask);
    k_apply2<<<dim3(6, 16, B_N), 256, 0, stream>>>(xbT, mask, out);
}